// Round 7
// baseline (231.064 us; speedup 1.0000x reference)
//
#include <hip/hip_runtime.h>
#include <hip/hip_bf16.h>

#define N_INS 16384
#define N_ATT 8192
#define KDIM  64
#define NCLU  64

typedef __attribute__((ext_vector_type(8))) short bf16x8;
typedef __attribute__((ext_vector_type(4))) float f32x4;

// ws layout (bytes) — every buffer fully overwritten each launch, NO zero-init:
// 0:       bf16 Ucb[8192*64] (1 MiB, fragment-order tiles)
// 1048576: float segparts[192][4096] (3 MiB; [0,128)=Ur blocks, [128,192)=Uc)
// 4194304: float Gpart[2048]
// 4202496: float cpr[128*64]
// 4235264: float cpc[64*64]
// 4251648: float Aseg[4096]
// 4268032: float Bseg[4096]
// 4284416: double Uupart[192]
#define OFF_UCB    0
#define OFF_SEGP   1048576
#define OFF_GPART  4194304
#define OFF_CPR    4202496
#define OFF_CPC    4235264
#define OFF_ASEG   4251648
#define OFF_BSEG   4268032
#define OFF_UUP    4284416

__device__ __forceinline__ unsigned short f2bf(float x) {
    unsigned u = __float_as_uint(x);
    u = (u + 0x7FFFu + ((u >> 16) & 1u)) >> 16;   // RNE
    return (unsigned short)u;
}

__device__ __forceinline__ float wave_red(float v) {
#pragma unroll
    for (int o = 32; o > 0; o >>= 1) v += __shfl_down(v, o, 64);
    return v;
}

// ---- prep: convert Uc->bf16 (fragment-order tiles) + column-sum partials ----
// Ucb: tile t=row>>4 (2KB, 16 rows); lane ℓ=(quad*16+m) fragment at tile+ℓ*16 /
// tile+1024+ℓ*16, i.e. chunk q of row m at (q<4 ? q*256+m*16 : 1024+(q-4)*256+m*16).
// blocks [0,128):   convert (2 chunks/thread)
// blocks [128,256): Ur colsum partials (128 rows) -> cpr (plain stores)
// blocks [256,320): Uc colsum partials (128 rows) -> cpc (plain stores)
__global__ void k_prep(const float* __restrict__ Ur, const float* __restrict__ Uc,
                       float* __restrict__ cpr, float* __restrict__ cpc,
                       unsigned short* __restrict__ Ucb) {
    int blk = blockIdx.x, tid = threadIdx.x;
    if (blk < 128) {
        int gid = blk * 256 + tid;
        for (int c = gid; c < N_ATT * 8; c += 32768) {
            int r = c >> 3, q = c & 7;
            const float4* src = (const float4*)(Uc + (size_t)r * 64 + q * 8);
            float4 x0 = src[0], x1 = src[1];
            uint4 v;
            v.x = (unsigned)f2bf(x0.x) | ((unsigned)f2bf(x0.y) << 16);
            v.y = (unsigned)f2bf(x0.z) | ((unsigned)f2bf(x0.w) << 16);
            v.z = (unsigned)f2bf(x1.x) | ((unsigned)f2bf(x1.y) << 16);
            v.w = (unsigned)f2bf(x1.z) | ((unsigned)f2bf(x1.w) << 16);
            int m = r & 15, t = r >> 4;
            int woff = (q < 4) ? (q * 256 + m * 16) : (1024 + (q - 4) * 256 + m * 16);
            *(uint4*)((unsigned char*)Ucb + (size_t)t * 2048 + woff) = v;
        }
        return;
    }
    __shared__ float cs2[256];
    bool isUr = blk < 256;
    int b = isUr ? (blk - 128) : (blk - 256);
    const float* base = (isUr ? Ur : Uc) + (size_t)b * 128 * KDIM;
    float* dst = (isUr ? cpr : cpc) + b * 64;
    int col = tid & 63, r0 = tid >> 6;
    float s = 0.f;
    for (int r = r0; r < 128; r += 4) s += base[r * KDIM + col];
    cs2[tid] = s;
    __syncthreads();
    if (tid < 64) dst[tid] = cs2[tid] + cs2[tid + 64] + cs2[tid + 128] + cs2[tid + 192];
}

// ---- pass: per-row argmax + weighted sum, COLUMN-PER-LANE (coalesced) ----
// R6 k_pass was 57us @ 0.5% VALU: 64 LDS atomics PER THREAD (16K lane-RMWs/wave)
// serialized the LDS pipe, plus row-per-thread loads gathered 64 lines/instr.
// Now: wave processes a row together -> 1 coalesced load + butterfly argmax/dot
// -> bin is wave-uniform -> ONE conflict-free LDS atomic instr per row.
// blocks [0,128): Ur, 128 rows each; [128,192): Uc, 128 rows each.
// Outputs: segparts[blk][4096], Uupart[blk] — plain stores only.
__global__ void k_pass(const float* __restrict__ Ur, const float* __restrict__ Uc,
                       const float* __restrict__ cpr, const float* __restrict__ cpc,
                       float* __restrict__ segparts, double* __restrict__ Uupart) {
    __shared__ float wv[64];
    __shared__ float Part[4096];
    __shared__ float psum[4];
    int blk = blockIdx.x, tid = threadIdx.x;
    int wvi = tid >> 6, lane = tid & 63;
    bool isUr = blk < 128;
    const float* M = isUr ? Ur : Uc;
    int base_row = (isUr ? blk : blk - 128) * 128;

    if (tid < 64) {
        const float* cp = isUr ? cpc : cpr;
        int nb = isUr ? 64 : 128;
        float s = 0.f;
        for (int p = 0; p < nb; ++p) s += cp[p * 64 + tid];
        wv[tid] = s;
    }
    for (int i = tid; i < 4096; i += 256) Part[i] = 0.f;
    __syncthreads();

    float wvl = wv[lane];
    const float* Mb = M + (size_t)(base_row + wvi * 32) * 64 + lane;
    float uu = 0.f;
    for (int c = 0; c < 4; ++c) {               // 8 rows per chunk, loads batched
        float vr[8];
#pragma unroll
        for (int k = 0; k < 8; ++k)
            vr[k] = Mb[(size_t)(c * 8 + k) * 64];
#pragma unroll
        for (int k = 0; k < 8; ++k) {
            float v = vr[k];
            float mx = v; int mi = lane; float s = v * wvl;
#pragma unroll
            for (int off = 32; off > 0; off >>= 1) {
                float omx = __shfl_xor(mx, off, 64);
                int   omi = __shfl_xor(mi, off, 64);
                s += __shfl_xor(s, off, 64);
                if (omx > mx || (omx == mx && omi < mi)) { mx = omx; mi = omi; }
            }
            // mi, s now uniform across the wave
            atomicAdd(&Part[mi * 64 + lane], v);   // 64 distinct addrs, 2/bank: free
            uu += s * __log2f(s);
        }
    }
    uu *= 0.015625f;                            // counted 64x (once per lane)
    if (lane == 0) psum[wvi] = uu;
    __syncthreads();
    float* sp = segparts + (size_t)blk * 4096;
    for (int i = tid; i < 4096; i += 256) sp[i] = Part[i];
    if (tid == 0)
        Uupart[blk] = (double)psum[0] + (double)psum[1]
                    + (double)psum[2] + (double)psum[3];
}

// ---- reduce segparts -> Aseg/Bseg (plain coalesced sums) ----
__global__ void k_red(const float* __restrict__ segparts,
                      float* __restrict__ Aseg, float* __restrict__ Bseg) {
    int j = blockIdx.x * 256 + threadIdx.x;     // 16 blocks -> j in [0,4096)
    float sa = 0.f, sb = 0.f;
    for (int b = 0; b < 128; ++b) sa += segparts[(size_t)b * 4096 + j];
    for (int b = 128; b < 192; ++b) sb += segparts[(size_t)b * 4096 + j];
    Aseg[j] = sa;
    Bseg[j] = sb;
}

// ---- heavy: G = sum_ij d_ij*log2(d_ij), bf16 MFMA + register-pipelined B ----
// (unchanged from R6 — dropped out of top-5)
__launch_bounds__(256)
__global__ void k_heavy(const float* __restrict__ Ur,
                        const unsigned char* __restrict__ Ucb,
                        float* __restrict__ Gpart) {
    __shared__ float gsh[4];
    int tid = threadIdx.x;
    int wvi = tid >> 6, lane = tid & 63;
    int quad = lane >> 4, m = lane & 15;
    int rb = blockIdx.x & 127, cc = blockIdx.x >> 7;
    int row0 = rb * 128 + wvi * 32;

    bf16x8 a[2][2];
#pragma unroll
    for (int t = 0; t < 2; ++t) {
        int ridx = row0 + t * 16 + m;
        const float* rp = Ur + (size_t)ridx * 64 + quad * 8;
#pragma unroll
        for (int h = 0; h < 2; ++h) {
            const float* rph = rp + h * 32;
            float4 x0 = *(const float4*)rph;
            float4 x1 = *(const float4*)(rph + 4);
            bf16x8 f;
            f[0] = (short)f2bf(x0.x); f[1] = (short)f2bf(x0.y);
            f[2] = (short)f2bf(x0.z); f[3] = (short)f2bf(x0.w);
            f[4] = (short)f2bf(x1.x); f[5] = (short)f2bf(x1.y);
            f[6] = (short)f2bf(x1.z); f[7] = (short)f2bf(x1.w);
            a[t][h] = f;
        }
    }

    const unsigned char* gB = Ucb + (size_t)(cc * 32) * 2048 + lane * 16;
    bf16x8 c00 = *(const bf16x8*)(gB);
    bf16x8 c01 = *(const bf16x8*)(gB + 1024);
    bf16x8 c10 = *(const bf16x8*)(gB + 2048);
    bf16x8 c11 = *(const bf16x8*)(gB + 3072);

    float g = 0.f;
#pragma unroll 1
    for (int pt = 0; pt < 16; ++pt) {
        int npt = (pt < 15) ? (pt + 1) : 15;
        const unsigned char* nb = gB + (size_t)npt * 4096;
        bf16x8 n00 = *(const bf16x8*)(nb);
        bf16x8 n01 = *(const bf16x8*)(nb + 1024);
        bf16x8 n10 = *(const bf16x8*)(nb + 2048);
        bf16x8 n11 = *(const bf16x8*)(nb + 3072);

        f32x4 acc00 = {0.f, 0.f, 0.f, 0.f};
        f32x4 acc01 = {0.f, 0.f, 0.f, 0.f};
        f32x4 acc10 = {0.f, 0.f, 0.f, 0.f};
        f32x4 acc11 = {0.f, 0.f, 0.f, 0.f};
        acc00 = __builtin_amdgcn_mfma_f32_16x16x32_bf16(a[0][0], c00, acc00, 0, 0, 0);
        acc00 = __builtin_amdgcn_mfma_f32_16x16x32_bf16(a[0][1], c01, acc00, 0, 0, 0);
        acc10 = __builtin_amdgcn_mfma_f32_16x16x32_bf16(a[1][0], c00, acc10, 0, 0, 0);
        acc10 = __builtin_amdgcn_mfma_f32_16x16x32_bf16(a[1][1], c01, acc10, 0, 0, 0);
        acc01 = __builtin_amdgcn_mfma_f32_16x16x32_bf16(a[0][0], c10, acc01, 0, 0, 0);
        acc01 = __builtin_amdgcn_mfma_f32_16x16x32_bf16(a[0][1], c11, acc01, 0, 0, 0);
        acc11 = __builtin_amdgcn_mfma_f32_16x16x32_bf16(a[1][0], c10, acc11, 0, 0, 0);
        acc11 = __builtin_amdgcn_mfma_f32_16x16x32_bf16(a[1][1], c11, acc11, 0, 0, 0);
#pragma unroll
        for (int e = 0; e < 4; ++e) {
            float d0 = acc00[e]; g += d0 * __log2f(d0);
            float d1 = acc01[e]; g += d1 * __log2f(d1);
            float d2 = acc10[e]; g += d2 * __log2f(d2);
            float d3 = acc11[e]; g += d3 * __log2f(d3);
        }
        c00 = n00; c01 = n01; c10 = n10; c11 = n11;
    }
    float gw = wave_red(g);
    if (lane == 0) gsh[wvi] = gw;
    __syncthreads();
    if (tid == 0) Gpart[blockIdx.x] = gsh[0] + gsh[1] + gsh[2] + gsh[3];
}

// ---- final: S, G, Uu/Vv from partials; reduced-table MI; assemble loss ----
__global__ void k_final(const float* __restrict__ Aseg, const float* __restrict__ Bseg,
                        const float* __restrict__ cpr, const float* __restrict__ cpc,
                        const float* __restrict__ Gpart, const double* __restrict__ Uupart,
                        float* __restrict__ out) {
    __shared__ double Trr[4096];
    __shared__ double Prx[64], Pry[64];
    __shared__ double red[256];
    __shared__ double up[192];
    __shared__ double Ssh, Gsh, Uush, Vvsh;
    int tid = threadIdx.x;
    if (tid < 192) up[tid] = Uupart[tid];
    if (tid < 64) {
        double sa = 0.0, sb = 0.0;
        for (int p = 0; p < 128; ++p) sa += (double)cpr[p * 64 + tid];
        for (int p = 0; p < 64; ++p)  sb += (double)cpc[p * 64 + tid];
        red[tid] = sa * sb;
    }
    __syncthreads();
    if (tid == 0) {
        double s = 0.0;
        for (int k = 0; k < 64; ++k) s += red[k];
        Ssh = s;
    } else if (tid == 1) {
        double s = 0.0;
        for (int k = 0; k < 128; ++k) s += up[k];
        Uush = s;
    } else if (tid == 2) {
        double s = 0.0;
        for (int k = 128; k < 192; ++k) s += up[k];
        Vvsh = s;
    }
    __syncthreads();
    {
        double gp = 0.0;
        for (int i = tid; i < 2048; i += 256) gp += (double)Gpart[i];
        red[tid] = gp;
    }
    __syncthreads();
    for (int s2 = 128; s2 > 0; s2 >>= 1) {
        if (tid < s2) red[tid] += red[tid + s2];
        __syncthreads();
    }
    if (tid == 0) Gsh = red[0];
    __syncthreads();
    double S = Ssh;
    int p = tid >> 2, qb = (tid & 3) * 16;
    for (int q = qb; q < qb + 16; ++q) {
        double s = 0.0;
        for (int k = 0; k < 64; ++k)
            s += (double)Aseg[p * 64 + k] * (double)Bseg[q * 64 + k];
        Trr[p * 64 + q] = s / S;
    }
    __syncthreads();
    if (tid < 64) {
        double s = 0.0;
        for (int q = 0; q < 64; ++q) s += Trr[tid * 64 + q];
        Prx[tid] = s;
    } else if (tid < 128) {
        int q = tid - 64;
        double s = 0.0;
        for (int pp = 0; pp < 64; ++pp) s += Trr[pp * 64 + q];
        Pry[q] = s;
    }
    __syncthreads();
    const double EPSd = 1e-15;
    double part = 0.0;
    for (int i = tid; i < 4096; i += 256) {
        double t = Trr[i];
        double txy = Prx[i >> 6] * Pry[i & 63];
        part += t * log((t + EPSd) / (txy + EPSd));
    }
    red[tid] = part;
    __syncthreads();
    for (int s2 = 128; s2 > 0; s2 >>= 1) {
        if (tid < s2) red[tid] += red[tid + s2];
        __syncthreads();
    }
    if (tid == 0) {
        const double inv_ln2 = 1.4426950408889634;
        double mi_red = red[0] * inv_ln2;
        double G = Gsh, Uu = Uush, Vv = Vvsh;
        double log2S = log(S) * inv_ln2;
        double mi_org = G / S + log2S - (Uu + Vv) / S;
        double loss = log(1.0 + fabs(1.0 - mi_red / mi_org));
        out[0] = (float)loss;
    }
}

extern "C" void kernel_launch(void* const* d_in, const int* in_sizes, int n_in,
                              void* d_out, int out_size, void* d_ws, size_t ws_size,
                              hipStream_t stream) {
    const float* Ur = (const float*)d_in[0];
    const float* Uc = (const float*)d_in[1];
    float* out = (float*)d_out;
    char* ws = (char*)d_ws;
    unsigned short* Ucb = (unsigned short*)(ws + OFF_UCB);
    float* segparts = (float*)(ws + OFF_SEGP);
    float* Gpart = (float*)(ws + OFF_GPART);
    float* cpr   = (float*)(ws + OFF_CPR);
    float* cpc   = (float*)(ws + OFF_CPC);
    float* Aseg  = (float*)(ws + OFF_ASEG);
    float* Bseg  = (float*)(ws + OFF_BSEG);
    double* Uupart = (double*)(ws + OFF_UUP);

    k_prep<<<320, 256, 0, stream>>>(Ur, Uc, cpr, cpc, Ucb);
    k_pass<<<192, 256, 0, stream>>>(Ur, Uc, cpr, cpc, segparts, Uupart);
    k_red<<<16, 256, 0, stream>>>(segparts, Aseg, Bseg);
    k_heavy<<<2048, 256, 0, stream>>>(Ur, (const unsigned char*)Ucb, Gpart);
    k_final<<<1, 256, 0, stream>>>(Aseg, Bseg, cpr, cpc, Gpart, Uupart, out);
}

// Round 8
// 211.945 us; speedup vs baseline: 1.0902x; 1.0902x over previous
//
#include <hip/hip_runtime.h>
#include <hip/hip_bf16.h>

#define N_INS 16384
#define N_ATT 8192
#define KDIM  64
#define NCLU  64

typedef __attribute__((ext_vector_type(8))) short bf16x8;
typedef __attribute__((ext_vector_type(4))) float f32x4;

// ws layout (bytes) — every buffer fully overwritten each launch, NO zero-init:
// 0:       bf16 Ucb[8192*64] (1 MiB, fragment-order tiles)
// 1048576: float segparts[96][4096] (1.5 MiB; [0,64)=Ur blocks, [64,96)=Uc)
// 2621440: float Gpart[2048]
// 2629632: float cpr[128*64]
// 2662400: float cpc[64*64]
// 2678784: float Aseg[4096]
// 2695168: float Bseg[4096]
// 2711552: double Uupart[96]
#define OFF_UCB    0
#define OFF_SEGP   1048576
#define OFF_GPART  2621440
#define OFF_CPR    2629632
#define OFF_CPC    2662400
#define OFF_ASEG   2678784
#define OFF_BSEG   2695168
#define OFF_UUP    2711552

__device__ __forceinline__ unsigned short f2bf(float x) {
    unsigned u = __float_as_uint(x);
    u = (u + 0x7FFFu + ((u >> 16) & 1u)) >> 16;   // RNE
    return (unsigned short)u;
}

__device__ __forceinline__ float wave_red(float v) {
#pragma unroll
    for (int o = 32; o > 0; o >>= 1) v += __shfl_down(v, o, 64);
    return v;
}

// ---- prep: convert Uc->bf16 (fragment-order tiles) + column-sum partials ----
// Ucb: tile t=row>>4 (2KB, 16 rows); lane ℓ=(quad*16+m) fragment at tile+ℓ*16 /
// tile+1024+ℓ*16, i.e. chunk q of row m at (q<4 ? q*256+m*16 : 1024+(q-4)*256+m*16).
// blocks [0,128):   convert (2 chunks/thread)
// blocks [128,256): Ur colsum partials (128 rows) -> cpr (plain stores)
// blocks [256,320): Uc colsum partials (128 rows) -> cpc (plain stores)
__global__ void k_prep(const float* __restrict__ Ur, const float* __restrict__ Uc,
                       float* __restrict__ cpr, float* __restrict__ cpc,
                       unsigned short* __restrict__ Ucb) {
    int blk = blockIdx.x, tid = threadIdx.x;
    if (blk < 128) {
        int gid = blk * 256 + tid;
        for (int c = gid; c < N_ATT * 8; c += 32768) {
            int r = c >> 3, q = c & 7;
            const float4* src = (const float4*)(Uc + (size_t)r * 64 + q * 8);
            float4 x0 = src[0], x1 = src[1];
            uint4 v;
            v.x = (unsigned)f2bf(x0.x) | ((unsigned)f2bf(x0.y) << 16);
            v.y = (unsigned)f2bf(x0.z) | ((unsigned)f2bf(x0.w) << 16);
            v.z = (unsigned)f2bf(x1.x) | ((unsigned)f2bf(x1.y) << 16);
            v.w = (unsigned)f2bf(x1.z) | ((unsigned)f2bf(x1.w) << 16);
            int m = r & 15, t = r >> 4;
            int woff = (q < 4) ? (q * 256 + m * 16) : (1024 + (q - 4) * 256 + m * 16);
            *(uint4*)((unsigned char*)Ucb + (size_t)t * 2048 + woff) = v;
        }
        return;
    }
    __shared__ float cs2[256];
    bool isUr = blk < 256;
    int b = isUr ? (blk - 128) : (blk - 256);
    const float* base = (isUr ? Ur : Uc) + (size_t)b * 128 * KDIM;
    float* dst = (isUr ? cpr : cpc) + b * 64;
    int col = tid & 63, r0 = tid >> 6;
    float s = 0.f;
    for (int r = r0; r < 128; r += 4) s += base[r * KDIM + col];
    cs2[tid] = s;
    __syncthreads();
    if (tid < 64) dst[tid] = cs2[tid] + cs2[tid + 64] + cs2[tid + 128] + cs2[tid + 192];
}

// ---- pass: argmax + weighted sums. Two phases, near-zero DS-pipe pressure. ----
// R6 (16K LDS atomics/block) and R7 (128 rows x 18 dependent DS-pipe shuffles)
// both sat at ~58us: at 1 block/CU, DS-op latency chains are unhidden. Now:
// phase 1: thread-per-row, pure-VALU argmax+dot (loads gathered but independent,
//          6MB L2/L3-resident); bins -> LDS, u -> one wave_red per wave.
// phase 2: wave walks its 64 rows: broadcast bin read (free), coalesced global
//          row re-read, ONE fire-and-forget ds_add_f32 per row. 256 DS instrs
//          per block total vs R6's 16K, and none of them chain.
// blocks [0,64): Ur, 256 rows each; [64,96): Uc, 256 rows each.
__global__ void k_pass(const float* __restrict__ Ur, const float* __restrict__ Uc,
                       const float* __restrict__ cpr, const float* __restrict__ cpc,
                       float* __restrict__ segparts, double* __restrict__ Uupart) {
    __shared__ float wv[64];
    __shared__ float Part[4096];
    __shared__ int   bins[256];
    __shared__ float psum[4];
    int blk = blockIdx.x, tid = threadIdx.x;
    int wvi = tid >> 6, lane = tid & 63;
    bool isUr = blk < 64;
    const float* M = isUr ? Ur : Uc;
    int base_row = (isUr ? blk : blk - 64) * 256;

    if (tid < 64) {
        const float* cp = isUr ? cpc : cpr;
        int nb = isUr ? 64 : 128;
        float s = 0.f;
        for (int p = 0; p < nb; ++p) s += cp[p * 64 + tid];
        wv[tid] = s;
    }
    for (int i = tid; i < 4096; i += 256) Part[i] = 0.f;
    __syncthreads();

    // phase 1: row-per-thread argmax + dot (VALU only)
    {
        int row = base_row + tid;
        const float* rp = M + (size_t)row * KDIM;
        float best = -1e30f; int bidx = 0; float u = 0.f;
#pragma unroll
        for (int k = 0; k < 64; k += 4) {
            float4 v = *(const float4*)(rp + k);
            if (v.x > best) { best = v.x; bidx = k; }
            if (v.y > best) { best = v.y; bidx = k + 1; }
            if (v.z > best) { best = v.z; bidx = k + 2; }
            if (v.w > best) { best = v.w; bidx = k + 3; }
            u += v.x * wv[k] + v.y * wv[k + 1] + v.z * wv[k + 2] + v.w * wv[k + 3];
        }
        bins[tid] = bidx;
        float p = u * __log2f(u);
        float pw = wave_red(p);          // once per wave, not per row
        if (lane == 0) psum[wvi] = pw;
    }
    __syncthreads();

    // phase 2: segment-sum, one ds_add_f32 per row per wave
    {
        int r0 = wvi * 64;
        const float* Mb = M + (size_t)(base_row + r0) * 64 + lane;
#pragma unroll 4
        for (int r = 0; r < 64; ++r) {
            int b = bins[r0 + r];                       // broadcast: free
            float val = Mb[(size_t)r * 64];             // coalesced 256B
            atomicAdd(&Part[b * 64 + lane], val);       // fire-and-forget
        }
    }
    __syncthreads();
    float* sp = segparts + (size_t)blk * 4096;
    for (int i = tid; i < 4096; i += 256) sp[i] = Part[i];
    if (tid == 0)
        Uupart[blk] = (double)psum[0] + (double)psum[1]
                    + (double)psum[2] + (double)psum[3];
}

// ---- heavy (blocks <2048): G-sum via bf16 MFMA, register-pipelined B.
// ---- red   (blocks >=2048, 128 of them): fold segparts -> Aseg/Bseg.
// Merged into one launch: independent work, saves a serialized launch gap.
__launch_bounds__(256)
__global__ void k_heavy(const float* __restrict__ Ur,
                        const unsigned char* __restrict__ Ucb,
                        float* __restrict__ Gpart,
                        const float* __restrict__ segparts,
                        float* __restrict__ Aseg, float* __restrict__ Bseg) {
    __shared__ float smem[512];
    int tid = threadIdx.x;
    if (blockIdx.x >= 2048) {                    // ---- k_red path ----
        int bid = blockIdx.x - 2048;             // 0..127
        int j = bid * 32 + (tid & 31);
        int p = tid >> 5;                        // 0..7
        float sa = 0.f, sb = 0.f;
        for (int b = p * 8; b < p * 8 + 8; ++b)       sa += segparts[(size_t)b * 4096 + j];
        for (int b = 64 + p * 4; b < 64 + p * 4 + 4; ++b) sb += segparts[(size_t)b * 4096 + j];
        smem[tid] = sa; smem[256 + tid] = sb;
        __syncthreads();
        if (tid < 32) {
            float ta = 0.f, tb = 0.f;
#pragma unroll
            for (int pp = 0; pp < 8; ++pp) {
                ta += smem[pp * 32 + tid];
                tb += smem[256 + pp * 32 + tid];
            }
            Aseg[bid * 32 + tid] = ta;
            Bseg[bid * 32 + tid] = tb;
        }
        return;
    }
    int wvi = tid >> 6, lane = tid & 63;
    int quad = lane >> 4, m = lane & 15;
    int rb = blockIdx.x & 127, cc = blockIdx.x >> 7;
    int row0 = rb * 128 + wvi * 32;

    bf16x8 a[2][2];
#pragma unroll
    for (int t = 0; t < 2; ++t) {
        int ridx = row0 + t * 16 + m;
        const float* rp = Ur + (size_t)ridx * 64 + quad * 8;
#pragma unroll
        for (int h = 0; h < 2; ++h) {
            const float* rph = rp + h * 32;
            float4 x0 = *(const float4*)rph;
            float4 x1 = *(const float4*)(rph + 4);
            bf16x8 f;
            f[0] = (short)f2bf(x0.x); f[1] = (short)f2bf(x0.y);
            f[2] = (short)f2bf(x0.z); f[3] = (short)f2bf(x0.w);
            f[4] = (short)f2bf(x1.x); f[5] = (short)f2bf(x1.y);
            f[6] = (short)f2bf(x1.z); f[7] = (short)f2bf(x1.w);
            a[t][h] = f;
        }
    }

    const unsigned char* gB = Ucb + (size_t)(cc * 32) * 2048 + lane * 16;
    bf16x8 c00 = *(const bf16x8*)(gB);
    bf16x8 c01 = *(const bf16x8*)(gB + 1024);
    bf16x8 c10 = *(const bf16x8*)(gB + 2048);
    bf16x8 c11 = *(const bf16x8*)(gB + 3072);

    float g = 0.f;
#pragma unroll 1
    for (int pt = 0; pt < 16; ++pt) {
        int npt = (pt < 15) ? (pt + 1) : 15;
        const unsigned char* nb = gB + (size_t)npt * 4096;
        bf16x8 n00 = *(const bf16x8*)(nb);
        bf16x8 n01 = *(const bf16x8*)(nb + 1024);
        bf16x8 n10 = *(const bf16x8*)(nb + 2048);
        bf16x8 n11 = *(const bf16x8*)(nb + 3072);

        f32x4 acc00 = {0.f, 0.f, 0.f, 0.f};
        f32x4 acc01 = {0.f, 0.f, 0.f, 0.f};
        f32x4 acc10 = {0.f, 0.f, 0.f, 0.f};
        f32x4 acc11 = {0.f, 0.f, 0.f, 0.f};
        acc00 = __builtin_amdgcn_mfma_f32_16x16x32_bf16(a[0][0], c00, acc00, 0, 0, 0);
        acc00 = __builtin_amdgcn_mfma_f32_16x16x32_bf16(a[0][1], c01, acc00, 0, 0, 0);
        acc10 = __builtin_amdgcn_mfma_f32_16x16x32_bf16(a[1][0], c00, acc10, 0, 0, 0);
        acc10 = __builtin_amdgcn_mfma_f32_16x16x32_bf16(a[1][1], c01, acc10, 0, 0, 0);
        acc01 = __builtin_amdgcn_mfma_f32_16x16x32_bf16(a[0][0], c10, acc01, 0, 0, 0);
        acc01 = __builtin_amdgcn_mfma_f32_16x16x32_bf16(a[0][1], c11, acc01, 0, 0, 0);
        acc11 = __builtin_amdgcn_mfma_f32_16x16x32_bf16(a[1][0], c10, acc11, 0, 0, 0);
        acc11 = __builtin_amdgcn_mfma_f32_16x16x32_bf16(a[1][1], c11, acc11, 0, 0, 0);
#pragma unroll
        for (int e = 0; e < 4; ++e) {
            float d0 = acc00[e]; g += d0 * __log2f(d0);
            float d1 = acc01[e]; g += d1 * __log2f(d1);
            float d2 = acc10[e]; g += d2 * __log2f(d2);
            float d3 = acc11[e]; g += d3 * __log2f(d3);
        }
        c00 = n00; c01 = n01; c10 = n10; c11 = n11;
    }
    float gw = wave_red(g);
    if (lane == 0) smem[wvi] = gw;
    __syncthreads();
    if (tid == 0) Gpart[blockIdx.x] = smem[0] + smem[1] + smem[2] + smem[3];
}

// ---- final: S, G, Uu/Vv from partials; reduced-table MI; assemble loss ----
__global__ void k_final(const float* __restrict__ Aseg, const float* __restrict__ Bseg,
                        const float* __restrict__ cpr, const float* __restrict__ cpc,
                        const float* __restrict__ Gpart, const double* __restrict__ Uupart,
                        float* __restrict__ out) {
    __shared__ double Trr[4096];
    __shared__ double Prx[64], Pry[64];
    __shared__ double red[256];
    __shared__ double up[96];
    __shared__ double Ssh, Gsh, Uush, Vvsh;
    int tid = threadIdx.x;
    if (tid < 96) up[tid] = Uupart[tid];
    if (tid < 64) {
        double sa = 0.0, sb = 0.0;
        for (int p = 0; p < 128; ++p) sa += (double)cpr[p * 64 + tid];
        for (int p = 0; p < 64; ++p)  sb += (double)cpc[p * 64 + tid];
        red[tid] = sa * sb;
    }
    __syncthreads();
    if (tid == 0) {
        double s = 0.0;
        for (int k = 0; k < 64; ++k) s += red[k];
        Ssh = s;
    } else if (tid == 1) {
        double s = 0.0;
        for (int k = 0; k < 64; ++k) s += up[k];
        Uush = s;
    } else if (tid == 2) {
        double s = 0.0;
        for (int k = 64; k < 96; ++k) s += up[k];
        Vvsh = s;
    }
    __syncthreads();
    {
        double gp = 0.0;
        for (int i = tid; i < 2048; i += 256) gp += (double)Gpart[i];
        red[tid] = gp;
    }
    __syncthreads();
    for (int s2 = 128; s2 > 0; s2 >>= 1) {
        if (tid < s2) red[tid] += red[tid + s2];
        __syncthreads();
    }
    if (tid == 0) Gsh = red[0];
    __syncthreads();
    double S = Ssh;
    int p = tid >> 2, qb = (tid & 3) * 16;
    for (int q = qb; q < qb + 16; ++q) {
        double s = 0.0;
        for (int k = 0; k < 64; ++k)
            s += (double)Aseg[p * 64 + k] * (double)Bseg[q * 64 + k];
        Trr[p * 64 + q] = s / S;
    }
    __syncthreads();
    if (tid < 64) {
        double s = 0.0;
        for (int q = 0; q < 64; ++q) s += Trr[tid * 64 + q];
        Prx[tid] = s;
    } else if (tid < 128) {
        int q = tid - 64;
        double s = 0.0;
        for (int pp = 0; pp < 64; ++pp) s += Trr[pp * 64 + q];
        Pry[q] = s;
    }
    __syncthreads();
    const double EPSd = 1e-15;
    double part = 0.0;
    for (int i = tid; i < 4096; i += 256) {
        double t = Trr[i];
        double txy = Prx[i >> 6] * Pry[i & 63];
        part += t * log((t + EPSd) / (txy + EPSd));
    }
    red[tid] = part;
    __syncthreads();
    for (int s2 = 128; s2 > 0; s2 >>= 1) {
        if (tid < s2) red[tid] += red[tid + s2];
        __syncthreads();
    }
    if (tid == 0) {
        const double inv_ln2 = 1.4426950408889634;
        double mi_red = red[0] * inv_ln2;
        double G = Gsh, Uu = Uush, Vv = Vvsh;
        double log2S = log(S) * inv_ln2;
        double mi_org = G / S + log2S - (Uu + Vv) / S;
        double loss = log(1.0 + fabs(1.0 - mi_red / mi_org));
        out[0] = (float)loss;
    }
}

extern "C" void kernel_launch(void* const* d_in, const int* in_sizes, int n_in,
                              void* d_out, int out_size, void* d_ws, size_t ws_size,
                              hipStream_t stream) {
    const float* Ur = (const float*)d_in[0];
    const float* Uc = (const float*)d_in[1];
    float* out = (float*)d_out;
    char* ws = (char*)d_ws;
    unsigned short* Ucb = (unsigned short*)(ws + OFF_UCB);
    float* segparts = (float*)(ws + OFF_SEGP);
    float* Gpart = (float*)(ws + OFF_GPART);
    float* cpr   = (float*)(ws + OFF_CPR);
    float* cpc   = (float*)(ws + OFF_CPC);
    float* Aseg  = (float*)(ws + OFF_ASEG);
    float* Bseg  = (float*)(ws + OFF_BSEG);
    double* Uupart = (double*)(ws + OFF_UUP);

    k_prep<<<320, 256, 0, stream>>>(Ur, Uc, cpr, cpc, Ucb);
    k_pass<<<96, 256, 0, stream>>>(Ur, Uc, cpr, cpc, segparts, Uupart);
    k_heavy<<<2176, 256, 0, stream>>>(Ur, (const unsigned char*)Ucb, Gpart,
                                      segparts, Aseg, Bseg);
    k_final<<<1, 256, 0, stream>>>(Aseg, Bseg, cpr, cpc, Gpart, Uupart, out);
}